// Round 6
// baseline (346.306 us; speedup 1.0000x reference)
//
#include <hip/hip_runtime.h>
#include <math.h>

typedef __attribute__((ext_vector_type(8))) short bf16x8;
typedef __attribute__((ext_vector_type(4))) float f32x4;

#define NWMASK 192
#define SCALE_Q 0.17677669529663687f

__device__ __forceinline__ unsigned short f2bf(float f) {
  union { float f; unsigned u; } v; v.f = f;
  return (unsigned short)((v.u + 0x7fffu + ((v.u >> 16) & 1u)) >> 16);
}

__device__ __forceinline__ unsigned pkbf(float a, float b) {
#if defined(__has_builtin)
#if __has_builtin(__builtin_amdgcn_cvt_pk_bf16_f32)
  auto r = __builtin_amdgcn_cvt_pk_bf16_f32(a, b);
  union { decltype(r) v; unsigned u; } c; c.v = r; return c.u;
#else
  return (unsigned)f2bf(a) | ((unsigned)f2bf(b) << 16);
#endif
#else
  return (unsigned)f2bf(a) | ((unsigned)f2bf(b) << 16);
#endif
}

__device__ __forceinline__ void pack8s(unsigned short* dst, const float* src) {
  float4 lo = *(const float4*)(src);
  float4 hi = *(const float4*)(src + 4);
  uint4 pk;
  pk.x = pkbf(lo.x, lo.y); pk.y = pkbf(lo.z, lo.w);
  pk.z = pkbf(hi.x, hi.y); pk.w = pkbf(hi.z, hi.w);
  *(uint4*)dst = pk;
}

// ---- prep: blocks 0-47 wpack, 48-63 pbT (+lam on blk48), 64-255 maskT ----
__global__ void prep_kernel(const float* __restrict__ Wqkv, const float* __restrict__ Wqkv2,
                            const float* __restrict__ Wproj,
                            const float* __restrict__ Wp1, const float* __restrict__ bp1,
                            const float* __restrict__ Wp2, const float* __restrict__ bp2,
                            const float* __restrict__ mask,
                            const float* __restrict__ lq1, const float* __restrict__ lk1,
                            const float* __restrict__ lq2, const float* __restrict__ lk2,
                            unsigned short* __restrict__ Wb, float* __restrict__ pbT,
                            float* __restrict__ maskT, float* __restrict__ lamOut) {
  int bid = blockIdx.x;
  if (bid < 48) {
    int gid = bid * 256 + threadIdx.x;            // 12288 fragment groups
    int l15 = gid & 15, quad = (gid >> 4) & 3, ks = (gid >> 6) & 3, ft = gid >> 8;
    int row = ft * 16 + l15;
    const float* src = (row < 384) ? (Wqkv + (size_t)row * 128)
                     : (row < 640) ? (Wqkv2 + (size_t)(row - 384) * 128)
                                   : (Wproj + (size_t)(row - 640) * 128);
    pack8s(Wb + (size_t)gid * 8, src + ks * 32 + quad * 8);
  } else if (bid < 64) {
    int idx = (bid - 48) * 256 + threadIdx.x;     // (i,j), 4096 total
    int i = idx >> 6, j = idx & 63;
    float dx = (float)((i & 7) - (j & 7));
    float dy = -(float)((i >> 3) - (j >> 3));
    float r = sqrtf(dx*dx + dy*dy + 1e-9f);
    float theta = atan2f(dx, dy);
    float p0 = r * (1.0f / 9.899494936611665f);
    float p1 = (theta + 3.14159265358979323846f) * (1.0f / 6.283185307179586f);
    float a0 = 0.f, a1 = 0.f, a2 = 0.f, a3 = 0.f;
    for (int f = 0; f < 64; ++f) {
      float hpre = p0 * Wp1[2*f] + p1 * Wp1[2*f+1] + bp1[f];
      float g = 0.5f * hpre * (1.0f + erff(hpre * 0.70710678118654752f));
      a0 += Wp2[f]       * g;
      a1 += Wp2[64 + f]  * g;
      a2 += Wp2[128 + f] * g;
      a3 += Wp2[192 + f] * g;
    }
    int o = j * 64 + i;                           // transposed
    pbT[o]          = a0 + bp2[0];
    pbT[4096 + o]   = a1 + bp2[1];
    pbT[8192 + o]   = a2 + bp2[2];
    pbT[12288 + o]  = a3 + bp2[3];
    if (bid == 48 && threadIdx.x == 0) {
      float s1 = 0.f, s2 = 0.f;
      for (int k = 0; k < 16; ++k) { s1 += lq1[k]*lk1[k]; s2 += lq2[k]*lk2[k]; }
      lamOut[0] = expf(s1) - expf(s2) + 0.2f;
    }
  } else {
    // per-window LDS transpose, coalesced both sides
    __shared__ float tile[64][65];
    int wm = bid - 64;
    const float* src = mask + (size_t)wm * 4096;
#pragma unroll
    for (int u = 0; u < 4; ++u) {
      int o = u * 1024 + threadIdx.x * 4;
      float4 v = *(const float4*)(src + o);
      int r = o >> 6, c = o & 63;
      tile[r][c] = v.x; tile[r][c+1] = v.y; tile[r][c+2] = v.z; tile[r][c+3] = v.w;
    }
    __syncthreads();
    float* dst = maskT + (size_t)wm * 4096;
#pragma unroll
    for (int u = 0; u < 4; ++u) {
      int o = u * 1024 + threadIdx.x * 4;
      int c = o >> 6, r = o & 63;
      float4 v;
      v.x = tile[r][c]; v.y = tile[r+1][c]; v.z = tile[r+2][c]; v.w = tile[r+3][c];
      *(float4*)(dst + o) = v;
    }
  }
}

// ---- fused: one block = one window, 8 waves = 4 heads x 2 q-row-halves ----
// Wave w: head h=w>>1, q-half m=w&1 (rows Rb=m*32..+31).
// DUPLICATION: each wave projects FULL K2/K/V itself (pair waves write
// byte-identical values to the shared head buffers -> racing writes benign,
// own writes cover all reads via lgkmcnt -> NO producer/consumer barriers).
// Only 4 block barriers: B1 XB staged; Bk KB region reuse (K2 -> K);
// B2 XB free (OBUF overlay); B3 OBUF ready.
// LDS 80 KB (u16 smem[40960]), 2 blocks/CU @ __launch_bounds__(512,4):
//   XB [0,8192): x bf16 [64][128] swizzled; after B2 -> OBUF [64][128]
//   head h at 8192+h*8192: KB [64][32] (2048), VT [32 d][64 tok] (2048),
//     wave slots m: QB [32][32] (1024) -> P [32 q][64 k] (2048) at +4096+m*2048
// softmax: plain E=exp(s), unnormalized (row-sum cancels in RMSNorm).
__global__ __launch_bounds__(512, 4)
void fused_win(const float* __restrict__ x, const unsigned short* __restrict__ Wb,
               const float* __restrict__ bqkv, const float* __restrict__ bqkv2,
               const float* __restrict__ lamBuf,
               const float* __restrict__ subln, const float* __restrict__ bproj,
               const float* __restrict__ pbT, const float* __restrict__ maskT,
               float* __restrict__ out) {
  __shared__ unsigned short smem[40960];

  const int b = blockIdx.x;
  const int t = threadIdx.x;
  const int w = t >> 6;
  const int h = w >> 1;            // head
  const int m = w & 1;             // q-row half
  const int lane = t & 63;
  const int l15 = lane & 15;
  const int quad = lane >> 4;
  const int Rb = m * 32;
  const f32x4 zero4 = (f32x4){0.f, 0.f, 0.f, 0.f};
  const float lam = lamBuf[0];

  // ---- stage x -> XB ----
  {
    const float* xg = x + (size_t)b * 8192;
#pragma unroll
    for (int u = 0; u < 2; ++u) {
      int id = u * 512 + t;
      int r = id >> 4, c16 = id & 15;
      pack8s(&smem[r * 128 + ((c16 ^ (r & 7)) * 8)], xg + r * 128 + c16 * 8);
    }
  }
  __syncthreads();                                   // B1

  unsigned short* HB = smem + 8192 + h * 8192;
  unsigned short* KB = HB;                           // [64][32] swizzled (shared, dup-written)
  unsigned short* VT = HB + 2048;                    // [32 d][64 tok] (shared, dup-written)
  unsigned short* QB = HB + 4096 + m * 2048;         // [32][32] own; P [32][64] overlays
  unsigned short* PW = QB;

  auto ldXBo = [&](int mi, int ks) -> bf16x8 {       // own 32 rows
    int row = Rb + mi * 16 + l15;
    return *(const bf16x8*)(&smem[row * 128 + (((ks * 4 + quad) ^ (l15 & 7)) * 8)]);
  };
  auto ldXBf = [&](int mi, int ks) -> bf16x8 {       // full 64 rows
    int row = mi * 16 + l15;
    return *(const bf16x8*)(&smem[row * 128 + (((ks * 4 + quad) ^ (l15 & 7)) * 8)]);
  };
  auto ldWbF = [&](int ft, int ks) -> bf16x8 {
    return *(const bf16x8*)(Wb + ((((size_t)ft * 4 + ks) * 4 + quad) * 16 + l15) * 8);
  };

  // own 32 tokens x 32 dims, acc[2][2]
  auto projOwn = [&](int ft0, int ft1, f32x4 (&acc)[2][2]) {
#pragma unroll
    for (int mi = 0; mi < 2; ++mi) { acc[mi][0] = zero4; acc[mi][1] = zero4; }
#pragma unroll
    for (int ks = 0; ks < 4; ++ks) {
      bf16x8 w0 = ldWbF(ft0, ks), w1 = ldWbF(ft1, ks);
      bf16x8 xa[2];
#pragma unroll
      for (int mi = 0; mi < 2; ++mi) xa[mi] = ldXBo(mi, ks);
      __builtin_amdgcn_s_setprio(1);
#pragma unroll
      for (int mi = 0; mi < 2; ++mi) {
        acc[mi][0] = __builtin_amdgcn_mfma_f32_16x16x32_bf16(xa[mi], w0, acc[mi][0], 0, 0, 0);
        acc[mi][1] = __builtin_amdgcn_mfma_f32_16x16x32_bf16(xa[mi], w1, acc[mi][1], 0, 0, 0);
      }
      __builtin_amdgcn_s_setprio(0);
    }
  };
  // full 64 tokens x 32 dims, acc[4][2]
  auto projFull = [&](int ft0, int ft1, f32x4 (&acc)[4][2]) {
#pragma unroll
    for (int mi = 0; mi < 4; ++mi) { acc[mi][0] = zero4; acc[mi][1] = zero4; }
#pragma unroll
    for (int ks = 0; ks < 4; ++ks) {
      bf16x8 w0 = ldWbF(ft0, ks), w1 = ldWbF(ft1, ks);
      bf16x8 xa[4];
#pragma unroll
      for (int mi = 0; mi < 4; ++mi) xa[mi] = ldXBf(mi, ks);
      __builtin_amdgcn_s_setprio(1);
#pragma unroll
      for (int mi = 0; mi < 4; ++mi) {
        acc[mi][0] = __builtin_amdgcn_mfma_f32_16x16x32_bf16(xa[mi], w0, acc[mi][0], 0, 0, 0);
        acc[mi][1] = __builtin_amdgcn_mfma_f32_16x16x32_bf16(xa[mi], w1, acc[mi][1], 0, 0, 0);
      }
      __builtin_amdgcn_s_setprio(0);
    }
  };
  // own Q [32][32] -> QB (local rows), swizzle ^(r&3) on 8-col groups
  auto storeQ = [&](f32x4 (&acc)[2][2], const float* bias, float sc) {
#pragma unroll
    for (int nj = 0; nj < 2; ++nj) {
      int c32 = nj * 16 + l15;
      float bv = bias[c32];
      int g = c32 >> 3, c7 = c32 & 7;
#pragma unroll
      for (int mi = 0; mi < 2; ++mi) {
        f32x4 a = acc[mi][nj];
        unsigned p01 = pkbf((a[0] + bv) * sc, (a[1] + bv) * sc);
        unsigned p23 = pkbf((a[2] + bv) * sc, (a[3] + bv) * sc);
        int r0 = mi * 16 + quad * 4;
        QB[(r0+0) * 32 + ((g ^ ((r0+0) & 3)) * 8) + c7] = (unsigned short)p01;
        QB[(r0+1) * 32 + ((g ^ ((r0+1) & 3)) * 8) + c7] = (unsigned short)(p01 >> 16);
        QB[(r0+2) * 32 + ((g ^ ((r0+2) & 3)) * 8) + c7] = (unsigned short)p23;
        QB[(r0+3) * 32 + ((g ^ ((r0+3) & 3)) * 8) + c7] = (unsigned short)(p23 >> 16);
      }
    }
  };
  // full K [64][32] -> KB (dup-written, identical values)
  auto storeK = [&](f32x4 (&acc)[4][2], const float* bias) {
#pragma unroll
    for (int nj = 0; nj < 2; ++nj) {
      int c32 = nj * 16 + l15;
      float bv = bias[c32];
      int g = c32 >> 3, c7 = c32 & 7;
#pragma unroll
      for (int mi = 0; mi < 4; ++mi) {
        f32x4 a = acc[mi][nj];
        unsigned p01 = pkbf(a[0] + bv, a[1] + bv);
        unsigned p23 = pkbf(a[2] + bv, a[3] + bv);
        int r0 = mi * 16 + quad * 4;
        KB[(r0+0) * 32 + ((g ^ ((r0+0) & 3)) * 8) + c7] = (unsigned short)p01;
        KB[(r0+1) * 32 + ((g ^ ((r0+1) & 3)) * 8) + c7] = (unsigned short)(p01 >> 16);
        KB[(r0+2) * 32 + ((g ^ ((r0+2) & 3)) * 8) + c7] = (unsigned short)p23;
        KB[(r0+3) * 32 + ((g ^ ((r0+3) & 3)) * 8) + c7] = (unsigned short)(p23 >> 16);
      }
    }
  };
  // S[2][4] (+)= Q(own) x K(all)^T, optional seed from pbT+maskT
  auto qkAll = [&](f32x4 (&S)[2][4], bool seed) {
    bf16x8 qa[2], kb[4];
#pragma unroll
    for (int mi = 0; mi < 2; ++mi) {
      int row = mi * 16 + l15;
      qa[mi] = *(const bf16x8*)(&QB[row * 32 + ((quad ^ (l15 & 3)) * 8)]);
    }
#pragma unroll
    for (int ni = 0; ni < 4; ++ni) {
      int row = ni * 16 + l15;
      kb[ni] = *(const bf16x8*)(&KB[row * 32 + ((quad ^ (l15 & 3)) * 8)]);
    }
    const float* pbh = pbT + h * 4096;
    const float* mkh = maskT + (size_t)(b % NWMASK) * 4096;
    __builtin_amdgcn_s_setprio(1);
#pragma unroll
    for (int mi = 0; mi < 2; ++mi)
#pragma unroll
      for (int ni = 0; ni < 4; ++ni) {
        f32x4 c;
        if (seed) {
          int off = (ni * 16 + l15) * 64 + Rb + mi * 16 + quad * 4;
          float4 p4 = *(const float4*)(pbh + off);
          float4 m4 = *(const float4*)(mkh + off);
          c[0] = p4.x + m4.x; c[1] = p4.y + m4.y;
          c[2] = p4.z + m4.z; c[3] = p4.w + m4.w;
        } else c = S[mi][ni];
        S[mi][ni] = __builtin_amdgcn_mfma_f32_16x16x32_bf16(qa[mi], kb[ni], c, 0, 0, 0);
      }
    __builtin_amdgcn_s_setprio(0);
  };

  // ===== secondary: q2' (own), k2 (full, dup) -> S = q2'k2 + pb + mask =====
  f32x4 S[2][4];
  {
    f32x4 accq[2][2];
    projOwn(24 + 2*h, 25 + 2*h, accq);
    storeQ(accq, bqkv2 + h*32, -lam * SCALE_Q);
    f32x4 acck[4][2];
    projFull(32 + 2*h, 33 + 2*h, acck);
    storeK(acck, bqkv2 + 128 + h*32);
    qkAll(S, true);
  }
  // primary Q proj before Bk (pure compute, KB untouched)
  f32x4 accq[2][2];
  projOwn(2*h, 1 + 2*h, accq);
  storeQ(accq, bqkv + h*32, SCALE_Q);
  __syncthreads();                                   // Bk: all qk2 KB-reads done
  {
    f32x4 acck[4][2];
    projFull(8 + 2*h, 9 + 2*h, acck);
    storeK(acck, bqkv + 128 + h*32);
    qkAll(S, false);
  }

  // ===== E = exp(S) packed bf16; S dies =====
  unsigned pe01[2][4], pe23[2][4];
#pragma unroll
  for (int mi = 0; mi < 2; ++mi)
#pragma unroll
    for (int reg = 0; reg < 4; ++reg) {
      pe01[mi][reg] = pkbf(__expf(S[mi][0][reg]), __expf(S[mi][1][reg]));
      pe23[mi][reg] = pkbf(__expf(S[mi][2][reg]), __expf(S[mi][3][reg]));
    }
  // ===== P (own rows, local) -> PW [32 q][64 k], swizzle ^(r&7) =====
#pragma unroll
  for (int mi = 0; mi < 2; ++mi)
#pragma unroll
    for (int reg = 0; reg < 4; ++reg) {
      int row = mi * 16 + quad * 4 + reg;
      unsigned short* prow = PW + row * 64;
      int sw = row & 7;
      unsigned v01 = pe01[mi][reg], v23 = pe23[mi][reg];
      prow[(((l15 >> 3) + 0) ^ sw) * 8 + (l15 & 7)] = (unsigned short)v01;
      prow[(((l15 >> 3) + 2) ^ sw) * 8 + (l15 & 7)] = (unsigned short)(v01 >> 16);
      prow[(((l15 >> 3) + 4) ^ sw) * 8 + (l15 & 7)] = (unsigned short)v23;
      prow[(((l15 >> 3) + 6) ^ sw) * 8 + (l15 & 7)] = (unsigned short)(v23 >> 16);
    }

  // ===== V projection (full, dup) — LAST XB reads =====
  f32x4 av[4][2];
  projFull(16 + 2*h, 17 + 2*h, av);
  // ===== VT [32 d][64 tok] (dup-written, identical) =====
  {
    const float* vbias = bqkv + 256 + h * 32;
#pragma unroll
    for (int nd = 0; nd < 2; ++nd) {
      int d = nd * 16 + l15;
      float bv = vbias[d];
#pragma unroll
      for (int mi = 0; mi < 4; ++mi) {
        int tok = mi * 16 + quad * 4;
        uint2 pk;
        pk.x = pkbf(av[mi][nd][0] + bv, av[mi][nd][1] + bv);
        pk.y = pkbf(av[mi][nd][2] + bv, av[mi][nd][3] + bv);
        *(uint2*)(&VT[d * 64 + (((tok >> 3) ^ (d & 7)) * 8) + (tok & 7)]) = pk;
      }
    }
  }

  // ===== PV: O = P(own rows) x VT^T; RMSNorm folds softmax sum =====
  float ov0[2][4], ov1[2][4];
  {
    f32x4 O[2][2];
#pragma unroll
    for (int mi = 0; mi < 2; ++mi) { O[mi][0] = zero4; O[mi][1] = zero4; }
#pragma unroll
    for (int kc = 0; kc < 2; ++kc) {
      bf16x8 pa[2], vb[2];
#pragma unroll
      for (int mi = 0; mi < 2; ++mi) {
        int row = mi * 16 + l15;
        pa[mi] = *(const bf16x8*)(&PW[row * 64 + (((kc * 4 + quad) ^ (row & 7)) * 8)]);
      }
#pragma unroll
      for (int nd = 0; nd < 2; ++nd) {
        int d = nd * 16 + l15;
        vb[nd] = *(const bf16x8*)(&VT[d * 64 + (((kc * 4 + quad) ^ (d & 7)) * 8)]);
      }
      __builtin_amdgcn_s_setprio(1);
#pragma unroll
      for (int mi = 0; mi < 2; ++mi) {
        O[mi][0] = __builtin_amdgcn_mfma_f32_16x16x32_bf16(pa[mi], vb[0], O[mi][0], 0, 0, 0);
        O[mi][1] = __builtin_amdgcn_mfma_f32_16x16x32_bf16(pa[mi], vb[1], O[mi][1], 0, 0, 0);
      }
      __builtin_amdgcn_s_setprio(0);
    }
    float sw0 = subln[l15] * 0.8f;
    float sw1 = subln[16 + l15] * 0.8f;
#pragma unroll
    for (int mi = 0; mi < 2; ++mi)
#pragma unroll
      for (int reg = 0; reg < 4; ++reg) {
        float a0 = O[mi][0][reg], a1 = O[mi][1][reg];
        float ss = a0 * a0 + a1 * a1;
        ss += __shfl_xor(ss, 1);
        ss += __shfl_xor(ss, 2);
        ss += __shfl_xor(ss, 4);
        ss += __shfl_xor(ss, 8);
        float rs = 1.0f / sqrtf(ss * (1.0f / 32.0f));   // eps*sum^2 negligible
        ov0[mi][reg] = a0 * rs * sw0;
        ov1[mi][reg] = a1 * rs * sw1;
      }
  }
  __syncthreads();                                   // B2: all XB reads done

  // ===== O -> OBUF [64][128] bf16 at smem[0,8192) (overlays XB) =====
  {
    int c0 = h * 32 + l15, c1 = h * 32 + 16 + l15;
#pragma unroll
    for (int mi = 0; mi < 2; ++mi)
#pragma unroll
      for (int reg = 0; reg < 4; ++reg) {
        int row = Rb + mi * 16 + quad * 4 + reg;
        unsigned short* orow = smem + row * 128;
        unsigned p = pkbf(ov0[mi][reg], ov1[mi][reg]);
        orow[(((c0 >> 3) ^ (row & 7)) * 8) + (c0 & 7)] = (unsigned short)p;
        orow[(((c1 >> 3) ^ (row & 7)) * 8) + (c1 & 7)] = (unsigned short)(p >> 16);
      }
  }
  __syncthreads();                                   // B3: OBUF ready

  // ===== out-projection: own 32 rows x cols h*32..+31 =====
  {
    f32x4 po[2][2];
#pragma unroll
    for (int mi = 0; mi < 2; ++mi) { po[mi][0] = zero4; po[mi][1] = zero4; }
#pragma unroll
    for (int ks = 0; ks < 4; ++ks) {
      bf16x8 oa[2];
#pragma unroll
      for (int mi = 0; mi < 2; ++mi) {
        int row = Rb + mi * 16 + l15;
        oa[mi] = *(const bf16x8*)(&smem[row * 128 + (((ks * 4 + quad) ^ (l15 & 7)) * 8)]);
      }
      bf16x8 w0 = ldWbF(40 + 2*h, ks), w1 = ldWbF(41 + 2*h, ks);
      __builtin_amdgcn_s_setprio(1);
#pragma unroll
      for (int mi = 0; mi < 2; ++mi) {
        po[mi][0] = __builtin_amdgcn_mfma_f32_16x16x32_bf16(oa[mi], w0, po[mi][0], 0, 0, 0);
        po[mi][1] = __builtin_amdgcn_mfma_f32_16x16x32_bf16(oa[mi], w1, po[mi][1], 0, 0, 0);
      }
      __builtin_amdgcn_s_setprio(0);
    }
    float* og = out + (size_t)b * 8192;
#pragma unroll
    for (int nt = 0; nt < 2; ++nt) {
      int col = h * 32 + nt * 16 + l15;
      float bp = bproj[col];
#pragma unroll
      for (int mi = 0; mi < 2; ++mi)
#pragma unroll
        for (int reg = 0; reg < 4; ++reg)
          og[(size_t)(Rb + mi * 16 + quad * 4 + reg) * 128 + col] = po[mi][nt][reg] + bp;
    }
  }
}

extern "C" void kernel_launch(void* const* d_in, const int* in_sizes, int n_in,
                              void* d_out, int out_size, void* d_ws, size_t ws_size,
                              hipStream_t stream) {
  (void)in_sizes; (void)n_in; (void)out_size; (void)ws_size;
  const float* x     = (const float*)d_in[0];
  const float* mask  = (const float*)d_in[1];
  const float* Wqkv  = (const float*)d_in[2];
  const float* bqkv  = (const float*)d_in[3];
  const float* Wqkv2 = (const float*)d_in[4];
  const float* bqkv2 = (const float*)d_in[5];
  const float* Wp1   = (const float*)d_in[6];
  const float* bp1   = (const float*)d_in[7];
  const float* Wp2   = (const float*)d_in[8];
  const float* bp2   = (const float*)d_in[9];
  const float* lq1   = (const float*)d_in[10];
  const float* lk1   = (const float*)d_in[11];
  const float* lq2   = (const float*)d_in[12];
  const float* lk2   = (const float*)d_in[13];
  const float* subln = (const float*)d_in[14];
  const float* Wproj = (const float*)d_in[15];
  const float* bproj = (const float*)d_in[16];
  float* out = (float*)d_out;

  unsigned short* Wb = (unsigned short*)d_ws;                         // 196608 B
  float* lamBuf = (float*)((char*)d_ws + 200704);                     // 4 B (spare)
  float* pbT   = (float*)((char*)d_ws + 262144);                      // 65536 B
  float* maskT = (float*)((char*)d_ws + 327680);                      // 3145728 B

  hipLaunchKernelGGL(prep_kernel, dim3(256), dim3(256), 0, stream,
                     Wqkv, Wqkv2, Wproj, Wp1, bp1, Wp2, bp2, mask,
                     lq1, lk1, lq2, lk2, Wb, pbT, maskT, lamBuf);
  hipLaunchKernelGGL(fused_win, dim3(3072), dim3(512), 0, stream,
                     x, Wb, bqkv, bqkv2, lamBuf, subln, bproj,
                     pbT, maskT, out);
}

// Round 7
// 325.497 us; speedup vs baseline: 1.0639x; 1.0639x over previous
//
#include <hip/hip_runtime.h>
#include <math.h>

typedef __attribute__((ext_vector_type(8))) short bf16x8;
typedef __attribute__((ext_vector_type(4))) float f32x4;

#define NWMASK 192
#define SCALE_Q 0.17677669529663687f

__device__ __forceinline__ unsigned short f2bf(float f) {
  union { float f; unsigned u; } v; v.f = f;
  return (unsigned short)((v.u + 0x7fffu + ((v.u >> 16) & 1u)) >> 16);
}

__device__ __forceinline__ unsigned pkbf(float a, float b) {
#if defined(__has_builtin)
#if __has_builtin(__builtin_amdgcn_cvt_pk_bf16_f32)
  auto r = __builtin_amdgcn_cvt_pk_bf16_f32(a, b);
  union { decltype(r) v; unsigned u; } c; c.v = r; return c.u;
#else
  return (unsigned)f2bf(a) | ((unsigned)f2bf(b) << 16);
#endif
#else
  return (unsigned)f2bf(a) | ((unsigned)f2bf(b) << 16);
#endif
}

__device__ __forceinline__ void pack8s(unsigned short* dst, const float* src) {
  float4 lo = *(const float4*)(src);
  float4 hi = *(const float4*)(src + 4);
  uint4 pk;
  pk.x = pkbf(lo.x, lo.y); pk.y = pkbf(lo.z, lo.w);
  pk.z = pkbf(hi.x, hi.y); pk.w = pkbf(hi.z, hi.w);
  *(uint4*)dst = pk;
}

// ---- prep: blocks 0-47 wpack, 48-63 pbN natural (+lam on blk48) ----
// maskT is GONE: the transposed-S dataflow consumes pb and mask in natural
// [query][key] layout, so fused_win reads the input mask directly.
__global__ void prep_kernel(const float* __restrict__ Wqkv, const float* __restrict__ Wqkv2,
                            const float* __restrict__ Wproj,
                            const float* __restrict__ Wp1, const float* __restrict__ bp1,
                            const float* __restrict__ Wp2, const float* __restrict__ bp2,
                            const float* __restrict__ lq1, const float* __restrict__ lk1,
                            const float* __restrict__ lq2, const float* __restrict__ lk2,
                            unsigned short* __restrict__ Wb, float* __restrict__ pbN,
                            float* __restrict__ lamOut) {
  int bid = blockIdx.x;
  if (bid < 48) {
    int gid = bid * 256 + threadIdx.x;            // 12288 fragment groups
    int l15 = gid & 15, quad = (gid >> 4) & 3, ks = (gid >> 6) & 3, ft = gid >> 8;
    int row = ft * 16 + l15;
    const float* src = (row < 384) ? (Wqkv + (size_t)row * 128)
                     : (row < 640) ? (Wqkv2 + (size_t)(row - 384) * 128)
                                   : (Wproj + (size_t)(row - 640) * 128);
    pack8s(Wb + (size_t)gid * 8, src + ks * 32 + quad * 8);
  } else {
    int idx = (bid - 48) * 256 + threadIdx.x;     // (i=query, j=key), 4096 total
    int i = idx >> 6, j = idx & 63;
    float dx = (float)((i & 7) - (j & 7));
    float dy = -(float)((i >> 3) - (j >> 3));
    float r = sqrtf(dx*dx + dy*dy + 1e-9f);
    float theta = atan2f(dx, dy);
    float p0 = r * (1.0f / 9.899494936611665f);
    float p1 = (theta + 3.14159265358979323846f) * (1.0f / 6.283185307179586f);
    float a0 = 0.f, a1 = 0.f, a2 = 0.f, a3 = 0.f;
    for (int f = 0; f < 64; ++f) {
      float hpre = p0 * Wp1[2*f] + p1 * Wp1[2*f+1] + bp1[f];
      float g = 0.5f * hpre * (1.0f + erff(hpre * 0.70710678118654752f));
      a0 += Wp2[f]       * g;
      a1 += Wp2[64 + f]  * g;
      a2 += Wp2[128 + f] * g;
      a3 += Wp2[192 + f] * g;
    }
    int o = i * 64 + j;                           // NATURAL [query][key]
    pbN[o]          = a0 + bp2[0];
    pbN[4096 + o]   = a1 + bp2[1];
    pbN[8192 + o]   = a2 + bp2[2];
    pbN[12288 + o]  = a3 + bp2[3];
    if (bid == 48 && threadIdx.x == 0) {
      float s1 = 0.f, s2 = 0.f;
      for (int k = 0; k < 16; ++k) { s1 += lq1[k]*lk1[k]; s2 += lq2[k]*lk2[k]; }
      lamOut[0] = expf(s1) - expf(s2) + 0.2f;
    }
  }
}

// ---- fully fused: one block = one window, wave w = head w (R0 structure) ----
// TRANSPOSED dataflow: Q/K proj as mfma(W,x) -> D[dim][tok] (uint2 stores);
// S^T = mfma(K,Q) -> seed reads pb/mask in NATURAL layout; exp(S^T) -> P[q][k]
// via uint2 stores; PV as mfma(V^T,P) -> O^T (2-shuffle RMS); out-proj as
// mfma(W,O) -> dwordx4 global stores. Same LDS plan + 4 barriers as R0.
// LDS 48 KB (u16 smem[24576]), 3 blocks/CU:
//   XB [0,8192): x bf16 [64][128] swizzled; after B2 wave w's VT=[w*2048,+2048)
//   PW_w [8192+w*4096,+4096): QBUF [0,2048) KBUF [2048,4096); later P [64][64]
//   OBUF (after B3) [8192,16384): O bf16 [64][128]
// softmax: plain E=exp(s), unnormalized (row-sum cancels in RMSNorm).
__global__ __launch_bounds__(256, 3)
void fused_win(const float* __restrict__ x, const unsigned short* __restrict__ Wb,
               const float* __restrict__ bqkv, const float* __restrict__ bqkv2,
               const float* __restrict__ lamBuf,
               const float* __restrict__ subln, const float* __restrict__ bproj,
               const float* __restrict__ pbN, const float* __restrict__ mask,
               float* __restrict__ out) {
  __shared__ unsigned short smem[24576];

  const int b = blockIdx.x;
  const int t = threadIdx.x;
  const int w = t >> 6;            // wave == head
  const int lane = t & 63;
  const int l15 = lane & 15;
  const int quad = lane >> 4;
  const int h = w;
  const f32x4 zero4 = (f32x4){0.f, 0.f, 0.f, 0.f};
  const float lam = lamBuf[0];

  // ---- stage x -> XB ----
  {
    const float* xg = x + (size_t)b * 8192;
#pragma unroll
    for (int u = 0; u < 4; ++u) {
      int id = u * 256 + t;
      int r = id >> 4, c16 = id & 15;
      pack8s(&smem[r * 128 + ((c16 ^ (r & 7)) * 8)], xg + r * 128 + c16 * 8);
    }
  }
  __syncthreads();                                   // B1

  unsigned short* PW = smem + 8192 + w * 4096;
  unsigned short* QB = PW;                           // [64 tok][32 d] swizzled
  unsigned short* KB = PW + 2048;                    // [64 tok][32 d] swizzled

  auto ldXB = [&](int mi, int ks) -> bf16x8 {
    int row = mi * 16 + l15;
    return *(const bf16x8*)(&smem[row * 128 + (((ks * 4 + quad) ^ (l15 & 7)) * 8)]);
  };
  auto ldWbF = [&](int ft, int ks) -> bf16x8 {
    return *(const bf16x8*)(Wb + ((((size_t)ft * 4 + ks) * 4 + quad) * 16 + l15) * 8);
  };

  // transposed projection: acc[nj dim-tile][mi tok-tile], D[row=dim][col=tok]
  auto proj4T = [&](int ft0, int ft1, int ft2, int ft3, f32x4 (&acc)[4][4]) {
#pragma unroll
    for (int nj = 0; nj < 4; ++nj)
#pragma unroll
      for (int mi = 0; mi < 4; ++mi) acc[nj][mi] = zero4;
#pragma unroll
    for (int ks = 0; ks < 4; ++ks) {
      bf16x8 xa[4], wf[4];
#pragma unroll
      for (int mi = 0; mi < 4; ++mi) xa[mi] = ldXB(mi, ks);
      wf[0] = ldWbF(ft0, ks); wf[1] = ldWbF(ft1, ks);
      wf[2] = ldWbF(ft2, ks); wf[3] = ldWbF(ft3, ks);
      __builtin_amdgcn_s_setprio(1);
#pragma unroll
      for (int nj = 0; nj < 4; ++nj)
#pragma unroll
        for (int mi = 0; mi < 4; ++mi)
          acc[nj][mi] = __builtin_amdgcn_mfma_f32_16x16x32_bf16(wf[nj], xa[mi], acc[nj][mi], 0, 0, 0);
      __builtin_amdgcn_s_setprio(0);
    }
  };
  // tiles 0,1 -> QB (scaled scA); tiles 2,3 -> KB. uint2 stores along d.
  auto storeQKT = [&](f32x4 (&acc)[4][4], const float* biasA, const float* biasB, float scA) {
#pragma unroll
    for (int nj = 0; nj < 4; ++nj) {
      int njl = nj & 1;
      unsigned short* buf = (nj < 2) ? QB : KB;
      const float* bs = (nj < 2) ? biasA : biasB;
      float sc = (nj < 2) ? scA : 1.0f;
      float4 bv = *(const float4*)(bs + njl * 16 + quad * 4);
      int g = njl * 2 + (quad >> 1);
      int d7 = (quad & 1) * 4;
#pragma unroll
      for (int mi = 0; mi < 4; ++mi) {
        f32x4 a = acc[nj][mi];
        uint2 pk;
        pk.x = pkbf((a[0] + bv.x) * sc, (a[1] + bv.y) * sc);
        pk.y = pkbf((a[2] + bv.z) * sc, (a[3] + bv.w) * sc);
        int tok = mi * 16 + l15;
        *(uint2*)(&buf[tok * 32 + ((g ^ (tok & 3)) * 8) + d7]) = pk;
      }
    }
  };
  // S^T[kt][qt] (+)= K x Q^T; seed C from NATURAL pb+mask
  auto qkAllT = [&](f32x4 (&S)[4][4], bool seed) {
    bf16x8 qa[4], kb[4];
#pragma unroll
    for (int i = 0; i < 4; ++i) {
      int row = i * 16 + l15;
      qa[i] = *(const bf16x8*)(&QB[row * 32 + ((quad ^ (row & 3)) * 8)]);
      kb[i] = *(const bf16x8*)(&KB[row * 32 + ((quad ^ (row & 3)) * 8)]);
    }
    const float* pbh = pbN + h * 4096;
    const float* mkh = mask + (size_t)(b % NWMASK) * 4096;
    __builtin_amdgcn_s_setprio(1);
#pragma unroll
    for (int kt = 0; kt < 4; ++kt)
#pragma unroll
      for (int qt = 0; qt < 4; ++qt) {
        f32x4 c;
        if (seed) {
          int off = (qt * 16 + l15) * 64 + kt * 16 + quad * 4;
          float4 p4 = *(const float4*)(pbh + off);
          float4 m4 = *(const float4*)(mkh + off);
          c[0] = p4.x + m4.x; c[1] = p4.y + m4.y;
          c[2] = p4.z + m4.z; c[3] = p4.w + m4.w;
        } else c = S[kt][qt];
        S[kt][qt] = __builtin_amdgcn_mfma_f32_16x16x32_bf16(kb[kt], qa[qt], c, 0, 0, 0);
      }
    __builtin_amdgcn_s_setprio(0);
  };

  // ===== secondary: S^T = (q2+b)*(-lam*scale) k2^T + (pb+mask)^T-seed =====
  f32x4 S[4][4];
  {
    f32x4 acc[4][4];
    proj4T(24 + 2*h, 25 + 2*h, 32 + 2*h, 33 + 2*h, acc);
    storeQKT(acc, bqkv2 + h*32, bqkv2 + 128 + h*32, -lam * SCALE_Q);
    qkAllT(S, true);
  }
  // ===== primary: S^T += k q^T (C-chained) =====
  {
    f32x4 acc[4][4];
    proj4T(2*h, 1 + 2*h, 8 + 2*h, 9 + 2*h, acc);
    storeQKT(acc, bqkv + h*32, bqkv + 128 + h*32, SCALE_Q);
    qkAllT(S, false);
  }

  // ===== E = exp(S^T) -> P [64 q][64 k] (uint2 along k) =====
  {
    int d7 = (quad & 1) * 4;
#pragma unroll
    for (int kt = 0; kt < 4; ++kt)
#pragma unroll
      for (int qt = 0; qt < 4; ++qt) {
        uint2 pk;
        pk.x = pkbf(__expf(S[kt][qt][0]), __expf(S[kt][qt][1]));
        pk.y = pkbf(__expf(S[kt][qt][2]), __expf(S[kt][qt][3]));
        int q = qt * 16 + l15;
        int g = kt * 2 + (quad >> 1);
        *(uint2*)(&PW[q * 64 + ((g ^ (q & 7)) * 8) + d7]) = pk;
      }
  }

  // ===== v projection (unswapped: D[tok][d]) — LAST XB reads =====
  f32x4 av[4][2];
  {
#pragma unroll
    for (int mi = 0; mi < 4; ++mi) { av[mi][0] = zero4; av[mi][1] = zero4; }
#pragma unroll
    for (int ks = 0; ks < 4; ++ks) {
      bf16x8 xa[4];
#pragma unroll
      for (int mi = 0; mi < 4; ++mi) xa[mi] = ldXB(mi, ks);
      bf16x8 w0 = ldWbF(16 + 2*h, ks), w1 = ldWbF(17 + 2*h, ks);
      __builtin_amdgcn_s_setprio(1);
#pragma unroll
      for (int mi = 0; mi < 4; ++mi) {
        av[mi][0] = __builtin_amdgcn_mfma_f32_16x16x32_bf16(xa[mi], w0, av[mi][0], 0, 0, 0);
        av[mi][1] = __builtin_amdgcn_mfma_f32_16x16x32_bf16(xa[mi], w1, av[mi][1], 0, 0, 0);
      }
      __builtin_amdgcn_s_setprio(0);
    }
  }
  __syncthreads();                                   // B2: XB reads done everywhere

  // ===== VT [32 d][64 tok] into XB region (wave w's slice) =====
  unsigned short* VT = smem + w * 2048;
  {
    const float* vbias = bqkv + 256 + h * 32;
#pragma unroll
    for (int nd = 0; nd < 2; ++nd) {
      int d = nd * 16 + l15;
      float bv = vbias[d];
#pragma unroll
      for (int mi = 0; mi < 4; ++mi) {
        int tok0 = mi * 16 + quad * 4;
        uint2 pk;
        pk.x = pkbf(av[mi][nd][0] + bv, av[mi][nd][1] + bv);
        pk.y = pkbf(av[mi][nd][2] + bv, av[mi][nd][3] + bv);
        *(uint2*)(&VT[d * 64 + (((tok0 >> 3) ^ (d & 7)) * 8) + (tok0 & 7)]) = pk;
      }
    }
  }

  // ===== PV swapped: O^T[dt][qt] = V^T x P^T; RMS folds softmax sum =====
  f32x4 O[2][4];
  {
#pragma unroll
    for (int dt = 0; dt < 2; ++dt)
#pragma unroll
      for (int qt = 0; qt < 4; ++qt) O[dt][qt] = zero4;
#pragma unroll
    for (int kc = 0; kc < 2; ++kc) {
      bf16x8 vb[2], pa[4];
#pragma unroll
      for (int dt = 0; dt < 2; ++dt) {
        int d = dt * 16 + l15;
        vb[dt] = *(const bf16x8*)(&VT[d * 64 + (((kc * 4 + quad) ^ (d & 7)) * 8)]);
      }
#pragma unroll
      for (int qt = 0; qt < 4; ++qt) {
        int q = qt * 16 + l15;
        pa[qt] = *(const bf16x8*)(&PW[q * 64 + (((kc * 4 + quad) ^ (q & 7)) * 8)]);
      }
      __builtin_amdgcn_s_setprio(1);
#pragma unroll
      for (int dt = 0; dt < 2; ++dt)
#pragma unroll
        for (int qt = 0; qt < 4; ++qt)
          O[dt][qt] = __builtin_amdgcn_mfma_f32_16x16x32_bf16(vb[dt], pa[qt], O[dt][qt], 0, 0, 0);
      __builtin_amdgcn_s_setprio(0);
    }
    // RMSNorm over d (lane-local 8 squares + 2 shuffles over quad bits)
    float4 s0 = *(const float4*)(subln + quad * 4);
    float4 s1 = *(const float4*)(subln + 16 + quad * 4);
    s0.x *= 0.8f; s0.y *= 0.8f; s0.z *= 0.8f; s0.w *= 0.8f;
    s1.x *= 0.8f; s1.y *= 0.8f; s1.z *= 0.8f; s1.w *= 0.8f;
#pragma unroll
    for (int qt = 0; qt < 4; ++qt) {
      float ss = 0.f;
#pragma unroll
      for (int dt = 0; dt < 2; ++dt)
#pragma unroll
        for (int r = 0; r < 4; ++r) ss += O[dt][qt][r] * O[dt][qt][r];
      ss += __shfl_xor(ss, 16);
      ss += __shfl_xor(ss, 32);
      float rs = 1.0f / sqrtf(ss * (1.0f / 32.0f));   // eps*sum^2 negligible
      O[0][qt][0] *= rs * s0.x; O[0][qt][1] *= rs * s0.y;
      O[0][qt][2] *= rs * s0.z; O[0][qt][3] *= rs * s0.w;
      O[1][qt][0] *= rs * s1.x; O[1][qt][1] *= rs * s1.y;
      O[1][qt][2] *= rs * s1.z; O[1][qt][3] *= rs * s1.w;
    }
  }
  __syncthreads();                                   // B3: all PW/VT reads done

  // ===== O^T -> OBUF [64 tok][128] bf16 at smem[8192,16384) =====
  unsigned short* OB = smem + 8192;
  {
    int d7 = (quad & 1) * 4;
#pragma unroll
    for (int qt = 0; qt < 4; ++qt)
#pragma unroll
      for (int dt = 0; dt < 2; ++dt) {
        int q = qt * 16 + l15;
        int c0 = h * 32 + dt * 16 + quad * 4;
        int g = c0 >> 3;
        uint2 pk;
        pk.x = pkbf(O[dt][qt][0], O[dt][qt][1]);
        pk.y = pkbf(O[dt][qt][2], O[dt][qt][3]);
        *(uint2*)(&OB[q * 128 + ((g ^ (q & 7)) * 8) + d7]) = pk;
      }
  }
  __syncthreads();                                   // B4

  // ===== out-projection swapped: D[outcol][tok] -> dwordx4 stores =====
  {
    f32x4 po[2][4];
#pragma unroll
    for (int nt = 0; nt < 2; ++nt)
#pragma unroll
      for (int mi = 0; mi < 4; ++mi) po[nt][mi] = zero4;
#pragma unroll
    for (int ks = 0; ks < 4; ++ks) {
      bf16x8 oa[4];
#pragma unroll
      for (int mi = 0; mi < 4; ++mi) {
        int row = mi * 16 + l15;
        oa[mi] = *(const bf16x8*)(&OB[row * 128 + (((ks * 4 + quad) ^ (l15 & 7)) * 8)]);
      }
      bf16x8 w0 = ldWbF(40 + 2*w, ks), w1 = ldWbF(41 + 2*w, ks);
      __builtin_amdgcn_s_setprio(1);
#pragma unroll
      for (int mi = 0; mi < 4; ++mi) {
        po[0][mi] = __builtin_amdgcn_mfma_f32_16x16x32_bf16(w0, oa[mi], po[0][mi], 0, 0, 0);
        po[1][mi] = __builtin_amdgcn_mfma_f32_16x16x32_bf16(w1, oa[mi], po[1][mi], 0, 0, 0);
      }
      __builtin_amdgcn_s_setprio(0);
    }
    float* og = out + (size_t)b * 8192;
#pragma unroll
    for (int nt = 0; nt < 2; ++nt) {
      int oc = (2 * w + nt) * 16 + quad * 4;
      float4 bp = *(const float4*)(bproj + oc);
#pragma unroll
      for (int mi = 0; mi < 4; ++mi) {
        int tok = mi * 16 + l15;
        float4 st;
        st.x = po[nt][mi][0] + bp.x; st.y = po[nt][mi][1] + bp.y;
        st.z = po[nt][mi][2] + bp.z; st.w = po[nt][mi][3] + bp.w;
        *(float4*)(og + (size_t)tok * 128 + oc) = st;
      }
    }
  }
}

extern "C" void kernel_launch(void* const* d_in, const int* in_sizes, int n_in,
                              void* d_out, int out_size, void* d_ws, size_t ws_size,
                              hipStream_t stream) {
  (void)in_sizes; (void)n_in; (void)out_size; (void)ws_size;
  const float* x     = (const float*)d_in[0];
  const float* mask  = (const float*)d_in[1];
  const float* Wqkv  = (const float*)d_in[2];
  const float* bqkv  = (const float*)d_in[3];
  const float* Wqkv2 = (const float*)d_in[4];
  const float* bqkv2 = (const float*)d_in[5];
  const float* Wp1   = (const float*)d_in[6];
  const float* bp1   = (const float*)d_in[7];
  const float* Wp2   = (const float*)d_in[8];
  const float* bp2   = (const float*)d_in[9];
  const float* lq1   = (const float*)d_in[10];
  const float* lk1   = (const float*)d_in[11];
  const float* lq2   = (const float*)d_in[12];
  const float* lk2   = (const float*)d_in[13];
  const float* subln = (const float*)d_in[14];
  const float* Wproj = (const float*)d_in[15];
  const float* bproj = (const float*)d_in[16];
  float* out = (float*)d_out;

  unsigned short* Wb = (unsigned short*)d_ws;                         // 196608 B
  float* lamBuf = (float*)((char*)d_ws + 200704);                     // 4 B
  float* pbN    = (float*)((char*)d_ws + 262144);                     // 65536 B

  hipLaunchKernelGGL(prep_kernel, dim3(64), dim3(256), 0, stream,
                     Wqkv, Wqkv2, Wproj, Wp1, bp1, Wp2, bp2,
                     lq1, lk1, lq2, lk2, Wb, pbN, lamBuf);
  hipLaunchKernelGGL(fused_win, dim3(3072), dim3(256), 0, stream,
                     x, Wb, bqkv, bqkv2, lamBuf, subln, bproj,
                     pbN, mask, out);
}